// Round 15
// baseline (232.419 us; speedup 1.0000x reference)
//
#include <hip/hip_runtime.h>
#include <hip/hip_bf16.h>
#include <stdint.h>

// Problem constants
#define B_   2
#define T_   2048
#define D_   1024
#define H_   16
#define HD_  64
#define MEM_ 512
#define KV_  (MEM_ + T_)   // 2560
#define NIT2_ (KV_ / 128)  // 20 kv-tiles of 128

using bf16 = __bf16;
typedef __bf16 bf16x8 __attribute__((ext_vector_type(8)));
typedef float  f32x4  __attribute__((ext_vector_type(4)));
typedef short  s16x4  __attribute__((ext_vector_type(4)));

__device__ __forceinline__ f32x4 mfma16(bf16x8 a, bf16x8 b, f32x4 c) {
  return __builtin_amdgcn_mfma_f32_16x16x32_bf16(a, b, c, 0, 0, 0);
}
__device__ __forceinline__ f32x4 mfma16k16(s16x4 a, s16x4 b, f32x4 c) {
  return __builtin_amdgcn_mfma_f32_16x16x16bf16_1k(a, b, c, 0, 0, 0);
}

// Load 8 consecutive elements at element-offset `off`; f32 path converts.
template <bool F32>
__device__ __forceinline__ bf16x8 load8(const void* p, size_t off) {
  if constexpr (F32) {
    const float* q = (const float*)p + off;
    f32x4 u = *(const f32x4*)q;
    f32x4 v = *(const f32x4*)(q + 4);
    bf16x8 r;
    r[0] = (bf16)u[0]; r[1] = (bf16)u[1]; r[2] = (bf16)u[2]; r[3] = (bf16)u[3];
    r[4] = (bf16)v[0]; r[5] = (bf16)v[1]; r[6] = (bf16)v[2]; r[7] = (bf16)v[3];
    return r;
  } else {
    return *(const bf16x8*)((const bf16*)p + off);
  }
}

__device__ __forceinline__ unsigned short bf16_bits(float f) {
  bf16 h = (bf16)f;
  return __builtin_bit_cast(unsigned short, h);
}

__device__ __forceinline__ ushort4 pack4(f32x4 v) {
  ushort4 p;
  p.x = bf16_bits(v[0]); p.y = bf16_bits(v[1]);
  p.z = bf16_bits(v[2]); p.w = bf16_bits(v[3]);
  return p;
}

// ---------------------------------------------------------------------------
// GEMM (B^T form): C[M,N] = A[M,K] * W[N,K]^T.  128x128 tile, BK=32,
// 4 waves (2x2 of 64x64), register-staged LDS (f32 inputs converted to bf16
// in flight - the R5-measured fastest configuration for these shapes).
// EPI==0: scatter q/k -> [bh][t][64], v -> vt_ws[bh][hd][t] (transposed).
// EPI==1: bias add -> Cout [M][1024] f32.  APLANE: A is plane layout.
// FUSEFILL: blocks with blockIdx.y == 32 instead convert memory f32 ->
//           mem_k bf16 + mem_vt bf16 (transposed), grid-stride.
// ---------------------------------------------------------------------------
template <int EPI, bool AF32, bool WF32, bool APLANE, bool FUSEFILL>
__global__ __launch_bounds__(256) void gemm_bt(
    const void* __restrict__ A, const void* __restrict__ W,
    const float* __restrict__ bias,
    bf16* __restrict__ q_ws, bf16* __restrict__ k_ws, bf16* __restrict__ vt_ws,
    float* __restrict__ Cout, int K,
    const float* __restrict__ memory, bf16* __restrict__ mem_k,
    bf16* __restrict__ mem_vt) {
  __shared__ __align__(16) bf16 Als[128 * 32];
  __shared__ __align__(16) bf16 Bls[128 * 32];
  const int tid = threadIdx.x;

  if constexpr (FUSEFILL) {
    if (blockIdx.y == 32) {
      // fill: 131072 f32x4 items over 24 blocks x 256 threads
      for (int i = blockIdx.x * 256 + tid; i < 131072; i += 24 * 256) {
        size_t e = (size_t)i * 4;
        f32x4 v = *(const f32x4*)(memory + e);
        *(ushort4*)&mem_k[e] = pack4(v);
        int m = (int)(e >> 10), d = (int)(e & 1023);
#pragma unroll
        for (int j = 0; j < 4; j++)
          mem_vt[(size_t)(d + j) * MEM_ + m] = (bf16)v[j];
      }
      return;
    }
  }

  const int m0 = blockIdx.y * 128;
  const int n0 = blockIdx.x * 128;
  const int w = tid >> 6;
  const int lane = tid & 63;
  const int lx = lane & 15;
  const int quad = lane >> 4;
  const int amb = (w & 1) * 64;
  const int bnb = (w >> 1) * 64;
  const int r0 = tid >> 2, seg = tid & 3;   // staging coords

  f32x4 acc[4][4];
#pragma unroll
  for (int i = 0; i < 4; i++)
#pragma unroll
    for (int j = 0; j < 4; j++) acc[i][j] = (f32x4){0.f, 0.f, 0.f, 0.f};

  for (int k0 = 0; k0 < K; k0 += 32) {
    bf16x8 a0, a1;
    if constexpr (APLANE) {
      int c0 = k0 + seg * 8, h = c0 >> 6, hd = c0 & 63;
      int mA = m0 + r0, mB = m0 + 64 + r0;
      a0 = load8<false>(A,
          ((size_t)((mA >> 11) * H_ + h) * T_ + (mA & 2047)) * HD_ + hd);
      a1 = load8<false>(A,
          ((size_t)((mB >> 11) * H_ + h) * T_ + (mB & 2047)) * HD_ + hd);
    } else {
      a0 = load8<AF32>(A, (size_t)(m0 + r0) * K + k0 + seg * 8);
      a1 = load8<AF32>(A, (size_t)(m0 + 64 + r0) * K + k0 + seg * 8);
    }
    bf16x8 b0 = load8<WF32>(W, (size_t)(n0 + r0) * K + k0 + seg * 8);
    bf16x8 b1 = load8<WF32>(W, (size_t)(n0 + 64 + r0) * K + k0 + seg * 8);
    __syncthreads();   // prev iteration's LDS reads done
    *(bf16x8*)&Als[tid * 8] = a0;          // row-major [128][32]
    *(bf16x8*)&Als[2048 + tid * 8] = a1;
    *(bf16x8*)&Bls[tid * 8] = b0;
    *(bf16x8*)&Bls[2048 + tid * 8] = b1;
    __syncthreads();   // tiles valid

    bf16x8 af[4], bfr[4];
#pragma unroll
    for (int mt = 0; mt < 4; mt++)
      af[mt] = *(const bf16x8*)&Als[(amb + mt * 16 + lx) * 32 + quad * 8];
#pragma unroll
    for (int nt = 0; nt < 4; nt++)
      bfr[nt] = *(const bf16x8*)&Bls[(bnb + nt * 16 + lx) * 32 + quad * 8];
#pragma unroll
    for (int mt = 0; mt < 4; mt++)
#pragma unroll
      for (int nt = 0; nt < 4; nt++)
        acc[mt][nt] = mfma16(af[mt], bfr[nt], acc[mt][nt]);
  }

  // Epilogue. C/D layout: row = quad*4+reg (m), col = lane&15 (n).
  if (EPI == 0) {
#pragma unroll
    for (int mt = 0; mt < 4; mt++) {
      int mbase = m0 + amb + mt * 16 + quad * 4;
      int b = mbase >> 11;        // T=2048
      int t = mbase & 2047;
#pragma unroll
      for (int nt = 0; nt < 4; nt++) {
        int col = n0 + bnb + nt * 16 + lx;     // [0,3072)
        int which = col >> 10;                 // 0=q 1=k 2=v
        int d = col & 1023;
        int h = d >> 6, hdi = d & 63;
        int bh = b * H_ + h;
        if (which == 0) {
#pragma unroll
          for (int r = 0; r < 4; r++)
            q_ws[((size_t)bh * T_ + t + r) * HD_ + hdi] = (bf16)acc[mt][nt][r];
        } else if (which == 1) {
#pragma unroll
          for (int r = 0; r < 4; r++)
            k_ws[((size_t)bh * T_ + t + r) * HD_ + hdi] = (bf16)acc[mt][nt][r];
        } else {
          *(ushort4*)&vt_ws[((size_t)bh * HD_ + hdi) * T_ + t] =
              pack4(acc[mt][nt]);
        }
      }
    }
  } else {
#pragma unroll
    for (int nt = 0; nt < 4; nt++) {
      int col = n0 + bnb + nt * 16 + lx;
      float bias_f = bias[col];
#pragma unroll
      for (int mt = 0; mt < 4; mt++) {
        int mbase = m0 + amb + mt * 16 + quad * 4;
#pragma unroll
        for (int r = 0; r < 4; r++)
          Cout[(size_t)(mbase + r) * D_ + col] = acc[mt][nt][r] + bias_f;
      }
    }
  }
}

// ---------------------------------------------------------------------------
// Flash attention, LDS-staged + transpose trick + exp2 diet, kv-tile 128
// processed as two 64-kv half-passes inside ONE barrier pair (barrier count
// halved vs R14; inner loop and register pressure unchanged).
// 1 block = 128 q of one (b,h); 4 waves x 32 q; grid 512 (2 blocks/CU).
// Output written in place into q_ws.
// ---------------------------------------------------------------------------
__global__ __launch_bounds__(256, 2) void attn_kernel(
    bf16* __restrict__ q_ws, const bf16* __restrict__ k_ws,
    const bf16* __restrict__ vt_ws, const bf16* __restrict__ mem_k,
    const bf16* __restrict__ mem_vt) {
  __shared__ __align__(16) bf16 Kls[128][72];   // [kv][hd], pad 8
  __shared__ __align__(16) bf16 Vls[64][136];   // [hd][kv], pad 8
  const int tid = threadIdx.x;
  const int w = tid >> 6;
  const int lane = tid & 63;
  const int lx = lane & 15;
  const int quad = lane >> 4;
  const int bh = blockIdx.x & 31;      // XCD-locality
  const int qt = blockIdx.x >> 5;      // 16 q-tiles of 128
  const int q0 = qt * 128 + w * 32;
  const int h = bh & 15;

  // staging coords: K tile 128x64 (8 chunks/row), V tile 64x128 (16/row)
  const int srK = tid >> 3, scK = (tid & 7) * 8;
  const int srV = tid >> 4, scV = (tid & 15) * 8;

  bf16* qbase = q_ws + ((size_t)bh * T_ + q0) * HD_;

  // Q B-frags (k32); fold softmax scale AND log2(e) into Q
  const float QSCALE = 0.125f * 1.44269504089f;
  bf16x8 qf[2][2];
#pragma unroll
  for (int qg = 0; qg < 2; qg++)
#pragma unroll
    for (int hf = 0; hf < 2; hf++) {
      bf16x8 v = *(const bf16x8*)(qbase + (size_t)(qg * 16 + lx) * HD_ +
                                  hf * 32 + quad * 8);
#pragma unroll
      for (int i = 0; i < 8; i++)
        v[i] = (bf16)((float)v[i] * QSCALE);
      qf[qg][hf] = v;
    }

  const bf16* kplane = k_ws + (size_t)bh * T_ * HD_;
  const bf16* vtplane = vt_ws + (size_t)bh * HD_ * T_;
  const bf16* mkh = mem_k + h * HD_;
  const bf16* mvh = mem_vt + (size_t)h * HD_ * MEM_;

  f32x4 o[4][2];
#pragma unroll
  for (int mt = 0; mt < 4; mt++)
#pragma unroll
    for (int qg = 0; qg < 2; qg++) o[mt][qg] = (f32x4){0.f, 0.f, 0.f, 0.f};
  float lsum[2] = {0.f, 0.f};

  for (int it = 0; it < NIT2_; it++) {
    const int kv0 = it * 128;
    const bool memPart = kv0 < MEM_;   // 512 % 128 == 0: no straddle
    // ---- global -> regs: K rows kv0+srK+32j; V^T rows srV+16j ----
    bf16x8 kr[4], vr[4];
    if (memPart) {
#pragma unroll
      for (int j = 0; j < 4; j++) {
        kr[j] = *(const bf16x8*)(mkh + (size_t)(kv0 + srK + 32 * j) * D_ + scK);
        vr[j] = *(const bf16x8*)(mvh + (size_t)(srV + 16 * j) * MEM_ + kv0 + scV);
      }
    } else {
      const int t0 = kv0 - MEM_;
#pragma unroll
      for (int j = 0; j < 4; j++) {
        kr[j] = *(const bf16x8*)(kplane + (size_t)(t0 + srK + 32 * j) * HD_ + scK);
        vr[j] = *(const bf16x8*)(vtplane + (size_t)(srV + 16 * j) * T_ + t0 + scV);
      }
    }
    __syncthreads();   // prev iteration's LDS reads complete
#pragma unroll
    for (int j = 0; j < 4; j++) {
      *(bf16x8*)&Kls[srK + 32 * j][scK] = kr[j];
      *(bf16x8*)&Vls[srV + 16 * j][scV] = vr[j];
    }
    __syncthreads();   // tiles valid

#pragma unroll
    for (int half = 0; half < 2; half++) {
      const int ro = half * 64;     // K row offset / V col offset
      f32x4 s[4][2];
#pragma unroll
      for (int g = 0; g < 4; g++) {
        bf16x8 ka0 = *(const bf16x8*)&Kls[ro + g * 16 + lx][quad * 8];
        bf16x8 ka1 = *(const bf16x8*)&Kls[ro + g * 16 + lx][32 + quad * 8];
#pragma unroll
        for (int qg = 0; qg < 2; qg++) {
          s[g][qg] = (f32x4){0.f, 0.f, 0.f, 0.f};
          s[g][qg] = mfma16(ka0, qf[qg][0], s[g][qg]);
          s[g][qg] = mfma16(ka1, qf[qg][1], s[g][qg]);
        }
      }

      s16x4 pb[2][4];
#pragma unroll
      for (int qg = 0; qg < 2; qg++) {
        float ps = 0.f;
#pragma unroll
        for (int g = 0; g < 4; g++) {
#pragma unroll
          for (int r = 0; r < 4; r++) {
            float p = __builtin_amdgcn_exp2f(s[g][qg][r]);  // raw v_exp_f32
            ps += p;
            pb[qg][g][r] = (short)bf16_bits(p);
          }
        }
        lsum[qg] += ps;
      }

#pragma unroll
      for (int mt = 0; mt < 4; mt++) {
#pragma unroll
        for (int kk = 0; kk < 4; kk++) {
          s16x4 va = *(const s16x4*)&Vls[mt * 16 + lx][ro + kk * 16 + quad * 4];
#pragma unroll
          for (int qg = 0; qg < 2; qg++)
            o[mt][qg] = mfma16k16(va, pb[qg][kk], o[mt][qg]);
        }
      }
    }
  }

  float inv[2];
#pragma unroll
  for (int qg = 0; qg < 2; qg++) {
    float s2 = lsum[qg];
    s2 += __shfl_xor(s2, 16);
    s2 += __shfl_xor(s2, 32);
    inv[qg] = 1.f / s2;
  }

#pragma unroll
  for (int qg = 0; qg < 2; qg++) {
#pragma unroll
    for (int mt = 0; mt < 4; mt++) {
      f32x4 ov;
#pragma unroll
      for (int r = 0; r < 4; r++) ov[r] = o[mt][qg][r] * inv[qg];
      *(ushort4*)(qbase + (size_t)(qg * 16 + lx) * HD_ + mt * 16 + quad * 4)
          = pack4(ov);
    }
  }
}

// ---------------------------------------------------------------------------
extern "C" void kernel_launch(void* const* d_in, const int* in_sizes, int n_in,
                              void* d_out, int out_size, void* d_ws,
                              size_t ws_size, hipStream_t stream) {
  const void*  x      = d_in[0];                 // [B,T,D]   f32
  const void*  w_qkv  = d_in[1];                 // [3D,D]    f32
  const void*  w_out  = d_in[2];                 // [D,D]     f32
  const float* b_out  = (const float*)d_in[3];   // [D]       f32
  const float* memory = (const float*)d_in[4];   // [MEM,D]   f32

  char* ws = (char*)d_ws;
  bf16* q_ws   = (bf16*)(ws);                    // [32][2048][64]  8 MiB
  bf16* k_ws   = (bf16*)(ws + (8u << 20));       // [32][2048][64]  8 MiB
  bf16* vt_ws  = (bf16*)(ws + (16u << 20));      // [32][64][2048]  8 MiB
  bf16* mem_k  = (bf16*)(ws + (24u << 20));      // [512][1024]     1 MiB
  bf16* mem_vt = (bf16*)(ws + (25u << 20));      // [1024][512]     1 MiB
  float* out = (float*)d_out;                    // f32 per reference

  // QKV GEMM with fused memory-fill (blockIdx.y == 32 -> fill blocks)
  gemm_bt<0, true, true, false, true><<<dim3(24, 33), dim3(256), 0, stream>>>(
      x, w_qkv, nullptr, q_ws, k_ws, vt_ws, nullptr, 1024,
      memory, mem_k, mem_vt);
  attn_kernel<<<dim3(512), dim3(256), 0, stream>>>(
      q_ws, k_ws, vt_ws, mem_k, mem_vt);
  gemm_bt<1, false, true, true, false><<<dim3(8, 32), dim3(256), 0, stream>>>(
      q_ws, w_out, b_out, nullptr, nullptr, nullptr, out, 1024,
      nullptr, nullptr, nullptr);
}

// Round 16
// 224.806 us; speedup vs baseline: 1.0339x; 1.0339x over previous
//
#include <hip/hip_runtime.h>
#include <hip/hip_bf16.h>
#include <stdint.h>

// Problem constants
#define B_   2
#define T_   2048
#define D_   1024
#define H_   16
#define HD_  64
#define MEM_ 512
#define KV_  (MEM_ + T_)   // 2560
#define NIT2_ (KV_ / 128)  // 20 kv-tiles of 128

using bf16 = __bf16;
typedef __bf16 bf16x8 __attribute__((ext_vector_type(8)));
typedef float  f32x4  __attribute__((ext_vector_type(4)));
typedef short  s16x4  __attribute__((ext_vector_type(4)));

__device__ __forceinline__ f32x4 mfma16(bf16x8 a, bf16x8 b, f32x4 c) {
  return __builtin_amdgcn_mfma_f32_16x16x32_bf16(a, b, c, 0, 0, 0);
}
__device__ __forceinline__ f32x4 mfma16k16(s16x4 a, s16x4 b, f32x4 c) {
  return __builtin_amdgcn_mfma_f32_16x16x16bf16_1k(a, b, c, 0, 0, 0);
}

// Load 8 consecutive elements at element-offset `off`; f32 path converts.
template <bool F32>
__device__ __forceinline__ bf16x8 load8(const void* p, size_t off) {
  if constexpr (F32) {
    const float* q = (const float*)p + off;
    f32x4 u = *(const f32x4*)q;
    f32x4 v = *(const f32x4*)(q + 4);
    bf16x8 r;
    r[0] = (bf16)u[0]; r[1] = (bf16)u[1]; r[2] = (bf16)u[2]; r[3] = (bf16)u[3];
    r[4] = (bf16)v[0]; r[5] = (bf16)v[1]; r[6] = (bf16)v[2]; r[7] = (bf16)v[3];
    return r;
  } else {
    return *(const bf16x8*)((const bf16*)p + off);
  }
}

__device__ __forceinline__ unsigned short bf16_bits(float f) {
  bf16 h = (bf16)f;
  return __builtin_bit_cast(unsigned short, h);
}

__device__ __forceinline__ ushort4 pack4(f32x4 v) {
  ushort4 p;
  p.x = bf16_bits(v[0]); p.y = bf16_bits(v[1]);
  p.z = bf16_bits(v[2]); p.w = bf16_bits(v[3]);
  return p;
}

// ---------------------------------------------------------------------------
// fill: memory [512][1024] f32 -> mem_k bf16 (same layout) and
//       mem_vt bf16 [1024][512] (transposed).  (R14 config - separate
//       dispatch; fusing into the GEMM grid caused block-round tail.)
// ---------------------------------------------------------------------------
__global__ void fill_mem(const float* __restrict__ memory,
                         bf16* __restrict__ mem_k, bf16* __restrict__ mem_vt) {
  int idx = blockIdx.x * 256 + threadIdx.x;   // [0, 512*1024)
  int m = idx >> 10, d = idx & 1023;
  bf16 v = (bf16)memory[idx];
  mem_k[idx] = v;
  mem_vt[(size_t)d * MEM_ + m] = v;
}

// ---------------------------------------------------------------------------
// GEMM (B^T form): C[M,N] = A[M,K] * W[N,K]^T.  128x128 tile, BK=32,
// 4 waves (2x2 of 64x64), register-staged LDS (f32 inputs converted to bf16
// in flight - the R5-measured fastest configuration for these shapes).
// EPI==0: scatter q/k -> [bh][t][64], v -> vt_ws[bh][hd][t] (transposed).
// EPI==1: bias add -> Cout [M][1024] f32.  APLANE: A is plane layout.
// ---------------------------------------------------------------------------
template <int EPI, bool AF32, bool WF32, bool APLANE>
__global__ __launch_bounds__(256) void gemm_bt(
    const void* __restrict__ A, const void* __restrict__ W,
    const float* __restrict__ bias,
    bf16* __restrict__ q_ws, bf16* __restrict__ k_ws, bf16* __restrict__ vt_ws,
    float* __restrict__ Cout, int K) {
  __shared__ __align__(16) bf16 Als[128 * 32];
  __shared__ __align__(16) bf16 Bls[128 * 32];
  const int m0 = blockIdx.y * 128;
  const int n0 = blockIdx.x * 128;
  const int tid = threadIdx.x;
  const int w = tid >> 6;
  const int lane = tid & 63;
  const int lx = lane & 15;
  const int quad = lane >> 4;
  const int amb = (w & 1) * 64;
  const int bnb = (w >> 1) * 64;
  const int r0 = tid >> 2, seg = tid & 3;   // staging coords

  f32x4 acc[4][4];
#pragma unroll
  for (int i = 0; i < 4; i++)
#pragma unroll
    for (int j = 0; j < 4; j++) acc[i][j] = (f32x4){0.f, 0.f, 0.f, 0.f};

  for (int k0 = 0; k0 < K; k0 += 32) {
    bf16x8 a0, a1;
    if constexpr (APLANE) {
      int c0 = k0 + seg * 8, h = c0 >> 6, hd = c0 & 63;
      int mA = m0 + r0, mB = m0 + 64 + r0;
      a0 = load8<false>(A,
          ((size_t)((mA >> 11) * H_ + h) * T_ + (mA & 2047)) * HD_ + hd);
      a1 = load8<false>(A,
          ((size_t)((mB >> 11) * H_ + h) * T_ + (mB & 2047)) * HD_ + hd);
    } else {
      a0 = load8<AF32>(A, (size_t)(m0 + r0) * K + k0 + seg * 8);
      a1 = load8<AF32>(A, (size_t)(m0 + 64 + r0) * K + k0 + seg * 8);
    }
    bf16x8 b0 = load8<WF32>(W, (size_t)(n0 + r0) * K + k0 + seg * 8);
    bf16x8 b1 = load8<WF32>(W, (size_t)(n0 + 64 + r0) * K + k0 + seg * 8);
    __syncthreads();   // prev iteration's LDS reads done
    *(bf16x8*)&Als[tid * 8] = a0;          // row-major [128][32]
    *(bf16x8*)&Als[2048 + tid * 8] = a1;
    *(bf16x8*)&Bls[tid * 8] = b0;
    *(bf16x8*)&Bls[2048 + tid * 8] = b1;
    __syncthreads();   // tiles valid

    bf16x8 af[4], bfr[4];
#pragma unroll
    for (int mt = 0; mt < 4; mt++)
      af[mt] = *(const bf16x8*)&Als[(amb + mt * 16 + lx) * 32 + quad * 8];
#pragma unroll
    for (int nt = 0; nt < 4; nt++)
      bfr[nt] = *(const bf16x8*)&Bls[(bnb + nt * 16 + lx) * 32 + quad * 8];
#pragma unroll
    for (int mt = 0; mt < 4; mt++)
#pragma unroll
      for (int nt = 0; nt < 4; nt++)
        acc[mt][nt] = mfma16(af[mt], bfr[nt], acc[mt][nt]);
  }

  // Epilogue. C/D layout: row = quad*4+reg (m), col = lane&15 (n).
  if (EPI == 0) {
#pragma unroll
    for (int mt = 0; mt < 4; mt++) {
      int mbase = m0 + amb + mt * 16 + quad * 4;
      int b = mbase >> 11;        // T=2048
      int t = mbase & 2047;
#pragma unroll
      for (int nt = 0; nt < 4; nt++) {
        int col = n0 + bnb + nt * 16 + lx;     // [0,3072)
        int which = col >> 10;                 // 0=q 1=k 2=v
        int d = col & 1023;
        int h = d >> 6, hdi = d & 63;
        int bh = b * H_ + h;
        if (which == 0) {
#pragma unroll
          for (int r = 0; r < 4; r++)
            q_ws[((size_t)bh * T_ + t + r) * HD_ + hdi] = (bf16)acc[mt][nt][r];
        } else if (which == 1) {
#pragma unroll
          for (int r = 0; r < 4; r++)
            k_ws[((size_t)bh * T_ + t + r) * HD_ + hdi] = (bf16)acc[mt][nt][r];
        } else {
          *(ushort4*)&vt_ws[((size_t)bh * HD_ + hdi) * T_ + t] =
              pack4(acc[mt][nt]);
        }
      }
    }
  } else {
#pragma unroll
    for (int nt = 0; nt < 4; nt++) {
      int col = n0 + bnb + nt * 16 + lx;
      float bias_f = bias[col];
#pragma unroll
      for (int mt = 0; mt < 4; mt++) {
        int mbase = m0 + amb + mt * 16 + quad * 4;
#pragma unroll
        for (int r = 0; r < 4; r++)
          Cout[(size_t)(mbase + r) * D_ + col] = acc[mt][nt][r] + bias_f;
      }
    }
  }
}

// ---------------------------------------------------------------------------
// Flash attention, LDS-staged + transpose trick + exp2 diet, kv-tile 128
// processed as two 64-kv half-passes inside ONE barrier pair (R15's good
// half: barrier count halved vs R14; inner loop unchanged).
// 1 block = 128 q of one (b,h); 4 waves x 32 q; grid 512 (2 blocks/CU).
// Output written in place into q_ws.
// ---------------------------------------------------------------------------
__global__ __launch_bounds__(256, 2) void attn_kernel(
    bf16* __restrict__ q_ws, const bf16* __restrict__ k_ws,
    const bf16* __restrict__ vt_ws, const bf16* __restrict__ mem_k,
    const bf16* __restrict__ mem_vt) {
  __shared__ __align__(16) bf16 Kls[128][72];   // [kv][hd], pad 8
  __shared__ __align__(16) bf16 Vls[64][136];   // [hd][kv], pad 8
  const int tid = threadIdx.x;
  const int w = tid >> 6;
  const int lane = tid & 63;
  const int lx = lane & 15;
  const int quad = lane >> 4;
  const int bh = blockIdx.x & 31;      // XCD-locality
  const int qt = blockIdx.x >> 5;      // 16 q-tiles of 128
  const int q0 = qt * 128 + w * 32;
  const int h = bh & 15;

  // staging coords: K tile 128x64 (8 chunks/row), V tile 64x128 (16/row)
  const int srK = tid >> 3, scK = (tid & 7) * 8;
  const int srV = tid >> 4, scV = (tid & 15) * 8;

  bf16* qbase = q_ws + ((size_t)bh * T_ + q0) * HD_;

  // Q B-frags (k32); fold softmax scale AND log2(e) into Q
  const float QSCALE = 0.125f * 1.44269504089f;
  bf16x8 qf[2][2];
#pragma unroll
  for (int qg = 0; qg < 2; qg++)
#pragma unroll
    for (int hf = 0; hf < 2; hf++) {
      bf16x8 v = *(const bf16x8*)(qbase + (size_t)(qg * 16 + lx) * HD_ +
                                  hf * 32 + quad * 8);
#pragma unroll
      for (int i = 0; i < 8; i++)
        v[i] = (bf16)((float)v[i] * QSCALE);
      qf[qg][hf] = v;
    }

  const bf16* kplane = k_ws + (size_t)bh * T_ * HD_;
  const bf16* vtplane = vt_ws + (size_t)bh * HD_ * T_;
  const bf16* mkh = mem_k + h * HD_;
  const bf16* mvh = mem_vt + (size_t)h * HD_ * MEM_;

  f32x4 o[4][2];
#pragma unroll
  for (int mt = 0; mt < 4; mt++)
#pragma unroll
    for (int qg = 0; qg < 2; qg++) o[mt][qg] = (f32x4){0.f, 0.f, 0.f, 0.f};
  float lsum[2] = {0.f, 0.f};

  for (int it = 0; it < NIT2_; it++) {
    const int kv0 = it * 128;
    const bool memPart = kv0 < MEM_;   // 512 % 128 == 0: no straddle
    bf16x8 kr[4], vr[4];
    if (memPart) {
#pragma unroll
      for (int j = 0; j < 4; j++) {
        kr[j] = *(const bf16x8*)(mkh + (size_t)(kv0 + srK + 32 * j) * D_ + scK);
        vr[j] = *(const bf16x8*)(mvh + (size_t)(srV + 16 * j) * MEM_ + kv0 + scV);
      }
    } else {
      const int t0 = kv0 - MEM_;
#pragma unroll
      for (int j = 0; j < 4; j++) {
        kr[j] = *(const bf16x8*)(kplane + (size_t)(t0 + srK + 32 * j) * HD_ + scK);
        vr[j] = *(const bf16x8*)(vtplane + (size_t)(srV + 16 * j) * T_ + t0 + scV);
      }
    }
    __syncthreads();   // prev iteration's LDS reads complete
#pragma unroll
    for (int j = 0; j < 4; j++) {
      *(bf16x8*)&Kls[srK + 32 * j][scK] = kr[j];
      *(bf16x8*)&Vls[srV + 16 * j][scV] = vr[j];
    }
    __syncthreads();   // tiles valid

#pragma unroll
    for (int half = 0; half < 2; half++) {
      const int ro = half * 64;     // K row offset / V col offset
      f32x4 s[4][2];
#pragma unroll
      for (int g = 0; g < 4; g++) {
        bf16x8 ka0 = *(const bf16x8*)&Kls[ro + g * 16 + lx][quad * 8];
        bf16x8 ka1 = *(const bf16x8*)&Kls[ro + g * 16 + lx][32 + quad * 8];
#pragma unroll
        for (int qg = 0; qg < 2; qg++) {
          s[g][qg] = (f32x4){0.f, 0.f, 0.f, 0.f};
          s[g][qg] = mfma16(ka0, qf[qg][0], s[g][qg]);
          s[g][qg] = mfma16(ka1, qf[qg][1], s[g][qg]);
        }
      }

      s16x4 pb[2][4];
#pragma unroll
      for (int qg = 0; qg < 2; qg++) {
        float ps = 0.f;
#pragma unroll
        for (int g = 0; g < 4; g++) {
#pragma unroll
          for (int r = 0; r < 4; r++) {
            float p = __builtin_amdgcn_exp2f(s[g][qg][r]);  // raw v_exp_f32
            ps += p;
            pb[qg][g][r] = (short)bf16_bits(p);
          }
        }
        lsum[qg] += ps;
      }

#pragma unroll
      for (int mt = 0; mt < 4; mt++) {
#pragma unroll
        for (int kk = 0; kk < 4; kk++) {
          s16x4 va = *(const s16x4*)&Vls[mt * 16 + lx][ro + kk * 16 + quad * 4];
#pragma unroll
          for (int qg = 0; qg < 2; qg++)
            o[mt][qg] = mfma16k16(va, pb[qg][kk], o[mt][qg]);
        }
      }
    }
  }

  float inv[2];
#pragma unroll
  for (int qg = 0; qg < 2; qg++) {
    float s2 = lsum[qg];
    s2 += __shfl_xor(s2, 16);
    s2 += __shfl_xor(s2, 32);
    inv[qg] = 1.f / s2;
  }

#pragma unroll
  for (int qg = 0; qg < 2; qg++) {
#pragma unroll
    for (int mt = 0; mt < 4; mt++) {
      f32x4 ov;
#pragma unroll
      for (int r = 0; r < 4; r++) ov[r] = o[mt][qg][r] * inv[qg];
      *(ushort4*)(qbase + (size_t)(qg * 16 + lx) * HD_ + mt * 16 + quad * 4)
          = pack4(ov);
    }
  }
}

// ---------------------------------------------------------------------------
extern "C" void kernel_launch(void* const* d_in, const int* in_sizes, int n_in,
                              void* d_out, int out_size, void* d_ws,
                              size_t ws_size, hipStream_t stream) {
  const void*  x      = d_in[0];                 // [B,T,D]   f32
  const void*  w_qkv  = d_in[1];                 // [3D,D]    f32
  const void*  w_out  = d_in[2];                 // [D,D]     f32
  const float* b_out  = (const float*)d_in[3];   // [D]       f32
  const float* memory = (const float*)d_in[4];   // [MEM,D]   f32

  char* ws = (char*)d_ws;
  bf16* q_ws   = (bf16*)(ws);                    // [32][2048][64]  8 MiB
  bf16* k_ws   = (bf16*)(ws + (8u << 20));       // [32][2048][64]  8 MiB
  bf16* vt_ws  = (bf16*)(ws + (16u << 20));      // [32][64][2048]  8 MiB
  bf16* mem_k  = (bf16*)(ws + (24u << 20));      // [512][1024]     1 MiB
  bf16* mem_vt = (bf16*)(ws + (25u << 20));      // [1024][512]     1 MiB
  float* out = (float*)d_out;                    // f32 per reference

  fill_mem<<<dim3(2048), dim3(256), 0, stream>>>(memory, mem_k, mem_vt);
  gemm_bt<0, true, true, false><<<dim3(24, 32), dim3(256), 0, stream>>>(
      x, w_qkv, nullptr, q_ws, k_ws, vt_ws, nullptr, 1024);
  attn_kernel<<<dim3(512), dim3(256), 0, stream>>>(
      q_ws, k_ws, vt_ws, mem_k, mem_vt);
  gemm_bt<1, false, true, true><<<dim3(8, 32), dim3(256), 0, stream>>>(
      q_ws, w_out, b_out, nullptr, nullptr, nullptr, out, 1024);
}